// Round 4
// baseline (709.212 us; speedup 1.0000x reference)
//
#include <hip/hip_runtime.h>
#include <hip/hip_bf16.h>

#define N_NODES 70000
#define N_PAD   70656    // 256 threads * 276
#define N_EDGES 800000
#define ROWLEN  1044
#define KDIM    1024
#define FEAT    128
#define NOUT    256      // stacked [y_l | y_r]
#define HIDDEN  37
#define CIN     148
#define TM      96       // gemm M-tile

typedef __attribute__((ext_vector_type(8))) short short8;
typedef __attribute__((ext_vector_type(4))) float f32x4;

static __device__ __forceinline__ unsigned short f2bf(float f) {
  unsigned int u = __float_as_uint(f);
  u += 0x7FFF + ((u >> 16) & 1);          // RNE
  return (unsigned short)(u >> 16);
}
static __device__ __forceinline__ float bf2f(unsigned int u) {
  return __uint_as_float(u << 16);
}
static __device__ __forceinline__ unsigned int pk2bf(float a, float b) {
  union { __hip_bfloat162 h; unsigned int u; } cv;
  cv.h = __float22bfloat162_rn(float2{a, b});   // v_cvt_pk_bf16_f32
  return cv.u;
}
static __device__ __forceinline__ void load_lds16(const void* g, void* l) {
  __builtin_amdgcn_global_load_lds(
      (const __attribute__((address_space(1))) unsigned int*)g,
      (__attribute__((address_space(3))) unsigned int*)l, 16, 0, 0);
}

// ---- W -> bf16 (stacked [Wl; Wr]) + zero cnt --------------------------------
__global__ __launch_bounds__(256) void cvt_w(
    const float* __restrict__ wl, const float* __restrict__ wr,
    unsigned short* __restrict__ wbf, unsigned int* __restrict__ z)
{
  const int i = blockIdx.x * 256 + threadIdx.x;   // float4 index, 0..65535
  const int half = (FEAT * KDIM) / 4;             // 32768
  const float* src = (i < half) ? wl : wr;
  const int j = (i < half) ? i : (i - half);
  const float4 v = ((const float4*)src)[j];
  uint2 u = make_uint2(pk2bf(v.x, v.y), pk2bf(v.z, v.w));
  ((uint2*)wbf)[i] = u;
  for (int k = i; k < N_PAD; k += 65536) z[k] = 0u;   // zero cnt (padded)
}

// ---- CSR build: histogram of dst; atomic return value = slot ----------------
__global__ __launch_bounds__(256) void hist(
    const int* __restrict__ edges, unsigned int* __restrict__ cnt,
    unsigned int* __restrict__ slot)
{
  const int e = blockIdx.x * 256 + threadIdx.x;   // grid = 3125 exact
  slot[e] = atomicAdd(&cnt[edges[N_EDGES + e]], 1u);
}

// ---- single-block exclusive scan: cnt[0..N_PAD) -> rs ----------------------
__global__ __launch_bounds__(256) void scan_all(
    const unsigned int* __restrict__ cnt, unsigned int* __restrict__ rs)
{
  __shared__ unsigned int s[256];
  const int t = threadIdx.x;
  const int base = t * 276;
  unsigned int sum = 0;
  for (int j = 0; j < 276; j += 4) {
    const uint4 v = *(const uint4*)(cnt + base + j);
    sum += v.x + v.y + v.z + v.w;
  }
  const unsigned int own = sum;
  s[t] = sum; __syncthreads();
  for (int off = 1; off < 256; off <<= 1) {       // Hillis-Steele inclusive
    const unsigned int x = (t >= off) ? s[t - off] : 0u;
    __syncthreads();
    s[t] += x;
    __syncthreads();
  }
  unsigned int run = s[t] - own;                  // exclusive base for this span
  for (int j = 0; j < 276; j += 4) {
    const uint4 v = *(const uint4*)(cnt + base + j);
    uint4 o;
    o.x = run; run += v.x;
    o.y = run; run += v.y;
    o.z = run; run += v.z;
    o.w = run; run += v.w;
    *(uint4*)(rs + base + j) = o;
  }
}

// ---- CSR fill, atomic-free: col[rs[dst] + slot[e]] = src --------------------
__global__ __launch_bounds__(256) void fill_csr(
    const int* __restrict__ edges, const unsigned int* __restrict__ rs,
    const unsigned int* __restrict__ slot, int* __restrict__ col)
{
  const int e = blockIdx.x * 256 + threadIdx.x;   // grid = 3125 exact
  col[rs[edges[N_EDGES + e]] + slot[e]] = edges[e];
}

// ---- y[m, 0:256] = feat[m, 0:1024] @ [Wl;Wr]^T (bf16 MFMA, 96x256 tile) -----
// B staged via global_load_lds with XOR swizzle (slot c16 ^ (n&7)) -> 2-way
// bank aliasing on ds_read_b128 (free, m136), no padding needed.
__global__ __launch_bounds__(256, 3) void gemm_sage(
    const float* __restrict__ feat,
    const unsigned short* __restrict__ wbf,
    unsigned short* __restrict__ y)
{
  __shared__ __align__(16) unsigned short As[TM][72];   // +8 pad: 144B stride
  __shared__ __align__(16) unsigned short Bs[256 * 64]; // swizzled, unpadded

  const int tid  = threadIdx.x;
  const int lane = tid & 63;
  const int wid  = tid >> 6;
  const int wm   = (wid & 1) * 48;       // wave tile: 48 x 128
  const int wn   = (wid >> 1) * 128;
  const int m0   = blockIdx.x * TM;

  f32x4 acc[3][8];
  const f32x4 zero = {0.f, 0.f, 0.f, 0.f};
  #pragma unroll
  for (int i = 0; i < 3; i++)
    #pragma unroll
    for (int j = 0; j < 8; j++) acc[i][j] = zero;

  const int c4    = tid & 15;   // A col group (4 floats)
  const int r0    = tid >> 4;   // A row base (16 rows/iter)
  const int rbase = wid * 64;   // B: wave-private 64-row span
  const int bs    = lane & 7;   // B LDS slot within row
  const int brow  = lane >> 3;  // B row offset within 8-row call

  for (int kk = 0; kk < KDIM; kk += 64) {
    // stage A: 96x64 fp32 -> bf16 (packed convert)
    #pragma unroll
    for (int i = 0; i < 6; i++) {
      int r = r0 + 16 * i;
      int m = m0 + r; if (m >= N_NODES) m = N_NODES - 1;   // clamp; not stored
      const float4 v = *(const float4*)(feat + (size_t)m * ROWLEN + kk + c4 * 4);
      uint2 u = make_uint2(pk2bf(v.x, v.y), pk2bf(v.z, v.w));
      *(uint2*)&As[r][c4 * 4] = u;
    }
    // stage B: 256x64 bf16 via async global->LDS, swizzled
    #pragma unroll
    for (int i = 0; i < 8; i++) {
      const int n   = rbase + i * 8 + brow;
      const int c16 = bs ^ (n & 7);
      load_lds16(wbf + (size_t)n * KDIM + kk + c16 * 8,
                 &Bs[(rbase + i * 8) * 64]);    // wave-uniform base; HW adds lane*16
    }
    __syncthreads();
    #pragma unroll
    for (int s = 0; s < 2; s++) {
      const int colk = s * 32 + (lane >> 4) * 8;  // frag: k = quad*8+j
      const int row  = lane & 15;
      short8 a[3];
      #pragma unroll
      for (int t = 0; t < 3; t++) a[t] = *(const short8*)&As[wm + t * 16 + row][colk];
      #pragma unroll
      for (int j = 0; j < 8; j++) {
        const int nr = wn + j * 16 + row;
        const short8 b = *(const short8*)&Bs[nr * 64 + (((colk >> 3) ^ (nr & 7)) * 8)];
        #pragma unroll
        for (int t = 0; t < 3; t++)
          acc[t][j] = __builtin_amdgcn_mfma_f32_16x16x32_bf16(a[t], b, acc[t][j], 0, 0, 0);
      }
    }
    __syncthreads();
  }

  // C/D layout: n = lane&15, m = (lane>>4)*4 + reg   [m89-verified]
  const int mb = m0 + wm + (lane >> 4) * 4;
  const int nb = wn + (lane & 15);
  #pragma unroll
  for (int t = 0; t < 3; t++) {
    #pragma unroll
    for (int r = 0; r < 4; r++) {
      const int m = mb + t * 16 + r;
      if (m < N_NODES) {
        #pragma unroll
        for (int j = 0; j < 8; j++)
          y[(size_t)m * NOUT + nb + j * 16] = f2bf(acc[t][j][r]);
      }
    }
  }
}

// ---- fused: CSR gather mean + sage-relu + concat + fc1 + BN + fc2 -----------
// 16 nodes/block (4 seq per wave); 2 edges per wave-iteration (32 lanes x uint2
// cover one 256B y-row); vbuf/hbuf are wave-private -> no per-node barriers.
__global__ __launch_bounds__(256) void gather_epilogue(
    const float* __restrict__ feat,
    const unsigned short* __restrict__ y,
    const unsigned int* __restrict__ rs,
    const unsigned int* __restrict__ cnt,
    const int* __restrict__ col,
    const float* __restrict__ b_sage_l,
    const float* __restrict__ fc1_w, const float* __restrict__ fc1_b,
    const float* __restrict__ fc2_w, const float* __restrict__ fc2_b,
    const float* __restrict__ bn_gamma, const float* __restrict__ bn_beta,
    const float* __restrict__ bn_mean, const float* __restrict__ bn_var,
    float* __restrict__ out)
{
  __shared__ float w1t[CIN][HIDDEN + 1];  // fc1_w transposed: conflict-free j-reads
  __shared__ float vbuf[4][CIN];
  __shared__ float hbuf[4][HIDDEN + 3];
  const int tid  = threadIdx.x;
  const int lane = tid & 63;
  const int w    = tid >> 6;

  for (int i = tid; i < HIDDEN * CIN; i += 256) {
    const int j = i / CIN;
    const int c = i - j * CIN;
    w1t[c][j] = fc1_w[i];
  }
  __syncthreads();

  const int sub = lane >> 5;       // which of the 2 edges this half-wave covers
  const int ch4 = lane & 31;       // channel group: bf16 channels ch4*4 .. +3

  #pragma unroll
  for (int rep = 0; rep < 4; rep++) {
    const int m  = blockIdx.x * 16 + w * 4 + rep;   // 70000 = 4375*16 exact
    const int e0 = (int)rs[m];
    const int n  = (int)cnt[m];

    float s0 = 0.f, s1 = 0.f, s2 = 0.f, s3 = 0.f;
    for (int i = 0; i < n; i += 2) {
      const int idx = i + sub;
      const bool act = idx < n;
      const int sa = col[e0 + (act ? idx : i)];
      const uint2 v = *(const uint2*)(y + (size_t)sa * NOUT + ch4 * 4);
      if (act) {
        s0 += bf2f(v.x & 0xFFFFu); s1 += bf2f(v.x >> 16);
        s2 += bf2f(v.y & 0xFFFFu); s3 += bf2f(v.y >> 16);
      }
    }
    s0 += __shfl_xor(s0, 32); s1 += __shfl_xor(s1, 32);
    s2 += __shfl_xor(s2, 32); s3 += __shfl_xor(s3, 32);

    const float inv = 1.0f / fmaxf((float)n, 1.0f);
    if (lane < 32) {
      const uint2 vr = *(const uint2*)(y + (size_t)m * NOUT + FEAT + ch4 * 4);
      const int c0 = ch4 * 4;
      vbuf[w][c0 + 0] = fmaxf(s0 * inv + b_sage_l[c0 + 0] + bf2f(vr.x & 0xFFFFu), 0.f);
      vbuf[w][c0 + 1] = fmaxf(s1 * inv + b_sage_l[c0 + 1] + bf2f(vr.x >> 16),     0.f);
      vbuf[w][c0 + 2] = fmaxf(s2 * inv + b_sage_l[c0 + 2] + bf2f(vr.y & 0xFFFFu), 0.f);
      vbuf[w][c0 + 3] = fmaxf(s3 * inv + b_sage_l[c0 + 3] + bf2f(vr.y >> 16),     0.f);
    }
    if (lane < CIN - FEAT)
      vbuf[w][FEAT + lane] = feat[(size_t)m * ROWLEN + KDIM + lane];  // extra 20

    // wave-private LDS RAW: ordered by lgkmcnt, no barrier needed
    if (lane < HIDDEN) {
      float h = fc1_b[lane];
      #pragma unroll 4
      for (int c = 0; c < CIN; c++) h += w1t[c][lane] * vbuf[w][c];
      h = fmaxf(h, 0.0f);
      h = (h - bn_mean[lane]) * rsqrtf(bn_var[lane] + 1e-5f) * bn_gamma[lane] + bn_beta[lane];
      hbuf[w][lane] = h;
    }
    if (lane < 3) {
      float o = fc2_b[lane];
      #pragma unroll
      for (int j = 0; j < HIDDEN; j++) o += fc2_w[lane * HIDDEN + j] * hbuf[w][j];
      out[(size_t)m * 3 + lane] = o;
    }
  }
}

// ---- workspace layout (~43.3 MB) --------------------------------------------
#define Y_OFF    0u
#define Y_BYTES  (N_NODES * NOUT * 2u)            // 35,840,000
#define WBF_OFF  Y_BYTES
#define WBF_BYTES (NOUT * KDIM * 2u)              //    524,288
#define CNT_OFF  (WBF_OFF + WBF_BYTES)            // 36,364,288
#define CNT_BYTES (N_PAD * 4u)                    //    282,624
#define RS_OFF   (CNT_OFF + CNT_BYTES)            // 36,646,912
#define SLOT_OFF (RS_OFF + CNT_BYTES)             // 36,929,536
#define SLOT_BYTES (N_EDGES * 4u)                 //  3,200,000
#define COL_OFF  (SLOT_OFF + SLOT_BYTES)          // 40,129,536

extern "C" void kernel_launch(void* const* d_in, const int* in_sizes, int n_in,
                              void* d_out, int out_size, void* d_ws, size_t ws_size,
                              hipStream_t stream) {
  const float* feat     = (const float*)d_in[0];
  const int*   edges    = (const int*)  d_in[1];
  // d_in[2] (edges2), d_in[3] (edge_features): unused by the reference
  const float* w_sage_l = (const float*)d_in[4];
  const float* b_sage_l = (const float*)d_in[5];
  const float* w_sage_r = (const float*)d_in[6];
  const float* fc1_w    = (const float*)d_in[7];
  const float* fc1_b    = (const float*)d_in[8];
  const float* fc2_w    = (const float*)d_in[9];
  const float* fc2_b    = (const float*)d_in[10];
  const float* bn_gamma = (const float*)d_in[11];
  const float* bn_beta  = (const float*)d_in[12];
  const float* bn_mean  = (const float*)d_in[13];
  const float* bn_var   = (const float*)d_in[14];
  float* out = (float*)d_out;

  char* ws = (char*)d_ws;
  unsigned short* y    = (unsigned short*)(ws + Y_OFF);
  unsigned short* wbf  = (unsigned short*)(ws + WBF_OFF);
  unsigned int*   cnt  = (unsigned int*)(ws + CNT_OFF);
  unsigned int*   rs   = (unsigned int*)(ws + RS_OFF);
  unsigned int*   slot = (unsigned int*)(ws + SLOT_OFF);
  int*            col  = (int*)(ws + COL_OFF);

  cvt_w<<<256, 256, 0, stream>>>(w_sage_l, w_sage_r, wbf, cnt);  // + zero cnt
  hist<<<N_EDGES / 256, 256, 0, stream>>>(edges, cnt, slot);
  scan_all<<<1, 256, 0, stream>>>(cnt, rs);
  fill_csr<<<N_EDGES / 256, 256, 0, stream>>>(edges, rs, slot, col);
  gemm_sage<<<(N_NODES + TM - 1) / TM, 256, 0, stream>>>(feat, wbf, y);
  gather_epilogue<<<N_NODES / 16, 256, 0, stream>>>(feat, y, rs, cnt, col, b_sage_l,
                                                    fc1_w, fc1_b, fc2_w, fc2_b,
                                                    bn_gamma, bn_beta, bn_mean, bn_var, out);
}